// Round 8
// baseline (743.214 us; speedup 1.0000x reference)
//
#include <hip/hip_runtime.h>
#include <hip/hip_bf16.h>
#include <math.h>

#define N_NODES 50000
#define N_EDGES 1600000
#define M_ROWS  100000   // 2 tokens per node

// ---------------- workspace layout (bytes) ----------------
// Lifetimes: xb, y, csr die after k_comb.
static const size_t XB_OFF   = 0;                 // xb bf16 [50000][320] = 32,000,000
static const size_t Y_OFF    = 32000000;          // y  bf16 [50000][320] = 32,000,000 -> 64,000,000
static const size_t CSR_OFF  = 64000000;          // int [E] = 6,400,000 -> 70,400,000
static const size_t COMB_OFF = 104000000;         // bf16 [100000][256] = 51,200,000 -> 155,200,000
static const size_t ROW_OFF  = 155200000;         // int [N+1]
static const size_t CNT_OFF  = 155400064;         // int [N]
static const size_t CUR_OFF  = 155600128;         // int [N]
static const size_t DIS_OFF  = 155800192;         // f32 [N]
static const size_t DINV_OFF = 156000256;         // f32 [N]
static const size_t BT_OFF   = 156200320;         // bf16 [576][256] = 294,912
static const size_t B2_OFF   = 156495232;         // f32 [576]
static const size_t WP_OFF   = 156497536;         // f32 [256]
static const size_t U_OFF    = 156498560;         // f32 [8][256]
static const size_t CH_OFF   = 156506752;         // f32 [8]
static const size_t FLAG_OFF = 156506816;         // int
static const size_t ACC_OFF  = 156506880;         // double
static const size_t WT2_OFF  = 156506944;         // bf16 [512][320] = 327,680
static const size_t WS_NEED  = 156834624;

typedef __attribute__((ext_vector_type(8))) short short8v;
typedef __attribute__((ext_vector_type(4))) float f32x4;

__device__ __forceinline__ float bf_lo(unsigned int u) { return __uint_as_float(u << 16); }
__device__ __forceinline__ float bf_hi(unsigned int u) { return __uint_as_float(u & 0xffff0000u); }
__device__ __forceinline__ float bf2f(unsigned short u) { return __uint_as_float((unsigned int)u << 16); }
__device__ __forceinline__ unsigned short f2bf(float f) {
    unsigned int x = __float_as_uint(f);
    return (unsigned short)((x + 0x7fffu + ((x >> 16) & 1u)) >> 16);   // RNE
}

// ---------------- kernels ----------------

__global__ void k_guard(float* out) { if (threadIdx.x == 0) out[0] = -12345.0f; }

// probe raw edge buffer: int64 layout has all odd int32 words == 0 (ids < 2^31)
__global__ void k_detect(const int* __restrict__ raw, int* __restrict__ flag) {
    if (raw[2 * threadIdx.x + 1] != 0) atomicOr(flag, 1);
}

__device__ __forceinline__ void load_edge(const int* raw, int is32, int e, int& s, int& d) {
    if (is32) { s = raw[e]; d = raw[N_EDGES + e]; }
    else      { s = raw[2 * (size_t)e]; d = raw[2 * ((size_t)N_EDGES + e)]; }
}

__global__ __launch_bounds__(256) void k_deg(const int* __restrict__ raw,
                                             const int* __restrict__ flag,
                                             int* __restrict__ cnt) {
    int e = blockIdx.x * 256 + threadIdx.x;
    if (e >= N_EDGES) return;
    int s, d; load_edge(raw, *flag, e, s, d);
    atomicAdd(&cnt[d], 1);
}

__global__ __launch_bounds__(256) void k_norm(const int* __restrict__ cnt,
                                              float* __restrict__ dis, float* __restrict__ dinv) {
    int n = blockIdx.x * 256 + threadIdx.x;
    if (n < N_NODES) {
        float d = 1.0f + (float)cnt[n];
        float r = rsqrtf(d);
        dis[n]  = r;
        dinv[n] = r * r;
    }
}

// exclusive scan of cnt[50000] -> rowptr[50001], single block of 1024
__global__ __launch_bounds__(1024) void k_scan(const int* __restrict__ cnt,
                                               int* __restrict__ rowptr) {
    __shared__ int part[1024];
    const int CH = 49;
    int tid = threadIdx.x;
    int base = tid * CH;
    int s = 0;
    for (int i = 0; i < CH; ++i) {
        int idx = base + i;
        if (idx < N_NODES) s += cnt[idx];
    }
    part[tid] = s;
    __syncthreads();
    for (int off = 1; off < 1024; off <<= 1) {
        int v = (tid >= off) ? part[tid - off] : 0;
        __syncthreads();
        part[tid] += v;
        __syncthreads();
    }
    int excl = (tid == 0) ? 0 : part[tid - 1];
    for (int i = 0; i < CH; ++i) {
        int idx = base + i;
        if (idx < N_NODES) { rowptr[idx] = excl; excl += cnt[idx]; }
    }
    if (tid == 1023) rowptr[N_NODES] = excl;
}

__global__ __launch_bounds__(256) void k_place(const int* __restrict__ raw,
                                               const int* __restrict__ flag,
                                               const int* __restrict__ rowptr,
                                               int* __restrict__ cur,
                                               int* __restrict__ csr) {
    int e = blockIdx.x * 256 + threadIdx.x;
    if (e >= N_EDGES) return;
    int s, d; load_edge(raw, *flag, e, s, d);
    int pos = rowptr[d] + atomicAdd(&cur[d], 1);
    csr[pos] = s;
}

// x fp32 [N][300] -> xb bf16 [N][320] (zero-padded K tail)
__global__ __launch_bounds__(256) void k_cvtx(const float* __restrict__ x,
                                              unsigned short* __restrict__ xb) {
    int idx = blockIdx.x * 256 + threadIdx.x;    // one per (row, 4-col group)
    int row = idx / 80, g = idx - row * 80;
    if (row >= N_NODES) return;
    int c0 = g * 4;
    ushort4 o;
    if (c0 < 300) {
        float4 v = *reinterpret_cast<const float4*>(x + (size_t)row * 300 + c0);
        o.x = f2bf(v.x); o.y = f2bf(v.y); o.z = f2bf(v.z); o.w = f2bf(v.w);
    } else {
        o = make_ushort4(0, 0, 0, 0);
    }
    *reinterpret_cast<ushort4*>(xb + (size_t)row * 320 + c0) = o;
}

// Wt2[j][k] = block-diag(Ws, Wf) transposed
__global__ __launch_bounds__(256) void k_wt2(const float* __restrict__ Ws,
                                             const float* __restrict__ Wf,
                                             unsigned short* __restrict__ Wt2) {
    int j = blockIdx.x;
    for (int k = threadIdx.x; k < 320; k += 256) {
        float v = 0.0f;
        if (j < 256) { if (k < 100) v = Ws[(size_t)k * 256 + j]; }
        else         { if (k >= 100 && k < 300) v = Wf[(size_t)(k - 100) * 256 + (j - 256)]; }
        Wt2[(size_t)j * 320 + k] = f2bf(v);
    }
}

// one wave per dst node, x-space aggregation, 8-edge unrolled for MLP:
// y[n] = dis[n] * sum_e dis[src]*xb[src] + dinv[n]*xb[n]   (320 ch, 40 active lanes)
__global__ __launch_bounds__(256) void k_aggx(const int* __restrict__ csr,
                                              const int* __restrict__ rowptr,
                                              const float* __restrict__ dis,
                                              const float* __restrict__ dinv,
                                              const unsigned short* __restrict__ xb,
                                              unsigned short* __restrict__ y) {
    int n    = blockIdx.x * 4 + (threadIdx.x >> 6);
    int lane = threadIdx.x & 63;
    if (n >= N_NODES || lane >= 40) return;
    int beg = rowptr[n], end = rowptr[n + 1];
    float a0=0,a1=0,a2=0,a3=0,a4=0,a5=0,a6=0,a7=0;
    int e = beg;
    for (; e + 8 <= end; e += 8) {
        int s0 = csr[e],   s1 = csr[e+1], s2 = csr[e+2], s3 = csr[e+3];
        int s4 = csr[e+4], s5 = csr[e+5], s6 = csr[e+6], s7 = csr[e+7];
        float c0 = dis[s0], c1 = dis[s1], c2 = dis[s2], c3 = dis[s3];
        float c4 = dis[s4], c5 = dis[s5], c6 = dis[s6], c7 = dis[s7];
        uint4 v0 = *reinterpret_cast<const uint4*>(xb + (size_t)s0 * 320 + lane * 8);
        uint4 v1 = *reinterpret_cast<const uint4*>(xb + (size_t)s1 * 320 + lane * 8);
        uint4 v2 = *reinterpret_cast<const uint4*>(xb + (size_t)s2 * 320 + lane * 8);
        uint4 v3 = *reinterpret_cast<const uint4*>(xb + (size_t)s3 * 320 + lane * 8);
        uint4 v4 = *reinterpret_cast<const uint4*>(xb + (size_t)s4 * 320 + lane * 8);
        uint4 v5 = *reinterpret_cast<const uint4*>(xb + (size_t)s5 * 320 + lane * 8);
        uint4 v6 = *reinterpret_cast<const uint4*>(xb + (size_t)s6 * 320 + lane * 8);
        uint4 v7 = *reinterpret_cast<const uint4*>(xb + (size_t)s7 * 320 + lane * 8);
        a0 += c0*bf_lo(v0.x); a1 += c0*bf_hi(v0.x); a2 += c0*bf_lo(v0.y); a3 += c0*bf_hi(v0.y);
        a4 += c0*bf_lo(v0.z); a5 += c0*bf_hi(v0.z); a6 += c0*bf_lo(v0.w); a7 += c0*bf_hi(v0.w);
        a0 += c1*bf_lo(v1.x); a1 += c1*bf_hi(v1.x); a2 += c1*bf_lo(v1.y); a3 += c1*bf_hi(v1.y);
        a4 += c1*bf_lo(v1.z); a5 += c1*bf_hi(v1.z); a6 += c1*bf_lo(v1.w); a7 += c1*bf_hi(v1.w);
        a0 += c2*bf_lo(v2.x); a1 += c2*bf_hi(v2.x); a2 += c2*bf_lo(v2.y); a3 += c2*bf_hi(v2.y);
        a4 += c2*bf_lo(v2.z); a5 += c2*bf_hi(v2.z); a6 += c2*bf_lo(v2.w); a7 += c2*bf_hi(v2.w);
        a0 += c3*bf_lo(v3.x); a1 += c3*bf_hi(v3.x); a2 += c3*bf_lo(v3.y); a3 += c3*bf_hi(v3.y);
        a4 += c3*bf_lo(v3.z); a5 += c3*bf_hi(v3.z); a6 += c3*bf_lo(v3.w); a7 += c3*bf_hi(v3.w);
        a0 += c4*bf_lo(v4.x); a1 += c4*bf_hi(v4.x); a2 += c4*bf_lo(v4.y); a3 += c4*bf_hi(v4.y);
        a4 += c4*bf_lo(v4.z); a5 += c4*bf_hi(v4.z); a6 += c4*bf_lo(v4.w); a7 += c4*bf_hi(v4.w);
        a0 += c5*bf_lo(v5.x); a1 += c5*bf_hi(v5.x); a2 += c5*bf_lo(v5.y); a3 += c5*bf_hi(v5.y);
        a4 += c5*bf_lo(v5.z); a5 += c5*bf_hi(v5.z); a6 += c5*bf_lo(v5.w); a7 += c5*bf_hi(v5.w);
        a0 += c6*bf_lo(v6.x); a1 += c6*bf_hi(v6.x); a2 += c6*bf_lo(v6.y); a3 += c6*bf_hi(v6.y);
        a4 += c6*bf_lo(v6.z); a5 += c6*bf_hi(v6.z); a6 += c6*bf_lo(v6.w); a7 += c6*bf_hi(v6.w);
        a0 += c7*bf_lo(v7.x); a1 += c7*bf_hi(v7.x); a2 += c7*bf_lo(v7.y); a3 += c7*bf_hi(v7.y);
        a4 += c7*bf_lo(v7.z); a5 += c7*bf_hi(v7.z); a6 += c7*bf_lo(v7.w); a7 += c7*bf_hi(v7.w);
    }
    for (; e < end; ++e) {
        int s = csr[e];
        float c = dis[s];
        uint4 v = *reinterpret_cast<const uint4*>(xb + (size_t)s * 320 + lane * 8);
        a0 += c*bf_lo(v.x); a1 += c*bf_hi(v.x); a2 += c*bf_lo(v.y); a3 += c*bf_hi(v.y);
        a4 += c*bf_lo(v.z); a5 += c*bf_hi(v.z); a6 += c*bf_lo(v.w); a7 += c*bf_hi(v.w);
    }
    float dn = dis[n], di = dinv[n];
    uint4 hv = *reinterpret_cast<const uint4*>(xb + (size_t)n * 320 + lane * 8);
    float r0 = dn*a0 + di*bf_lo(hv.x);
    float r1 = dn*a1 + di*bf_hi(hv.x);
    float r2 = dn*a2 + di*bf_lo(hv.y);
    float r3 = dn*a3 + di*bf_hi(hv.y);
    float r4 = dn*a4 + di*bf_lo(hv.z);
    float r5 = dn*a5 + di*bf_hi(hv.z);
    float r6 = dn*a6 + di*bf_lo(hv.w);
    float r7 = dn*a7 + di*bf_hi(hv.w);
    uint4 o;
    o.x = (unsigned int)f2bf(r0) | ((unsigned int)f2bf(r1) << 16);
    o.y = (unsigned int)f2bf(r2) | ((unsigned int)f2bf(r3) << 16);
    o.z = (unsigned int)f2bf(r4) | ((unsigned int)f2bf(r5) << 16);
    o.w = (unsigned int)f2bf(r6) | ((unsigned int)f2bf(r7) << 16);
    *reinterpret_cast<uint4*>(y + (size_t)n * 320 + lane * 8) = o;
}

// MFMA GEMM + fused bias/ReLU: comb = relu(y @ Wt2^T + bias), token-major layout
__global__ __launch_bounds__(256) void k_comb(const unsigned short* __restrict__ y,
                                              const unsigned short* __restrict__ Wt2,
                                              const float* __restrict__ bs,
                                              const float* __restrict__ bf,
                                              unsigned short* __restrict__ comb) {
    __shared__ __align__(16) unsigned short sA[64][40];
    __shared__ __align__(16) unsigned short sB[64][40];
    int tid  = threadIdx.x;
    int lane = tid & 63, wid = tid >> 6;
    int wm = wid >> 1, wn = wid & 1;
    int arow = tid >> 2, aseg = (tid & 3) * 8;
    int cblk = blockIdx.x, rblk = blockIdx.y;
    long grow = (long)rblk * 64 + arow;
    bool aval = grow < N_NODES;
    const unsigned short* aptr = y + grow * 320 + aseg;
    const unsigned short* bptr = Wt2 + ((long)cblk * 64 + arow) * 320 + aseg;

    f32x4 acc00 = {0,0,0,0}, acc01 = {0,0,0,0}, acc10 = {0,0,0,0}, acc11 = {0,0,0,0};
    int fr = lane & 15, fk = (lane >> 4) * 8;

    for (int ks = 0; ks < 10; ++ks) {
        uint4 av = aval ? *reinterpret_cast<const uint4*>(aptr + ks * 32) : make_uint4(0,0,0,0);
        uint4 bv = *reinterpret_cast<const uint4*>(bptr + ks * 32);
        __syncthreads();
        *reinterpret_cast<uint4*>(&sA[arow][aseg]) = av;
        *reinterpret_cast<uint4*>(&sB[arow][aseg]) = bv;
        __syncthreads();
        short8v a0 = *reinterpret_cast<const short8v*>(&sA[wm * 32 + fr][fk]);
        short8v a1 = *reinterpret_cast<const short8v*>(&sA[wm * 32 + 16 + fr][fk]);
        short8v b0 = *reinterpret_cast<const short8v*>(&sB[wn * 32 + fr][fk]);
        short8v b1 = *reinterpret_cast<const short8v*>(&sB[wn * 32 + 16 + fr][fk]);
        acc00 = __builtin_amdgcn_mfma_f32_16x16x32_bf16(a0, b0, acc00, 0, 0, 0);
        acc01 = __builtin_amdgcn_mfma_f32_16x16x32_bf16(a0, b1, acc01, 0, 0, 0);
        acc10 = __builtin_amdgcn_mfma_f32_16x16x32_bf16(a1, b0, acc10, 0, 0, 0);
        acc11 = __builtin_amdgcn_mfma_f32_16x16x32_bf16(a1, b1, acc11, 0, 0, 0);
    }

    int crow = rblk * 64 + wm * 32;
    int ccol = cblk * 64 + wn * 32;
    int rb = (lane >> 4) * 4;
    #pragma unroll
    for (int mn = 0; mn < 4; ++mn) {
        int m = mn >> 1, nn = mn & 1;
        f32x4 a = (mn == 0) ? acc00 : (mn == 1) ? acc01 : (mn == 2) ? acc10 : acc11;
        int col = ccol + nn * 16 + (lane & 15);
        int t  = col >> 8;          // token: 0 (s) / 1 (f)
        int c2 = col & 255;
        float bias = t ? bf[c2] : bs[c2];
        #pragma unroll
        for (int j = 0; j < 4; ++j) {
            int row = crow + m * 16 + rb + j;
            if (row < N_NODES)
                comb[(size_t)(2 * row + t) * 256 + c2] = f2bf(fmaxf(a[j] + bias, 0.0f));
        }
    }
}

// w'[i] = sum_j out_w[j] * out_proj_w[j][i]
__global__ __launch_bounds__(256) void k_wprime(const float* __restrict__ ow,
                                                const float* __restrict__ opw,
                                                float* __restrict__ wp) {
    int i = threadIdx.x;
    float s = 0.0f;
    for (int j = 0; j < 256; ++j) s += ow[j] * opw[j * 256 + i];
    wp[i] = s;
}

// u[h][i] = sum_d ipw[512+h*32+d][i] * w'[h*32+d] ;  c[h] = sum_d ipb[...]*w'[...]
__global__ __launch_bounds__(256) void k_u(const float* __restrict__ ipw,
                                           const float* __restrict__ ipb,
                                           const float* __restrict__ wp,
                                           float* __restrict__ u, float* __restrict__ ch) {
    int hd = blockIdx.x, i = threadIdx.x;
    float s = 0.0f;
    for (int d = 0; d < 32; ++d)
        s += ipw[(size_t)(512 + hd * 32 + d) * 256 + i] * wp[hd * 32 + d];
    u[hd * 256 + i] = s;
    if (i == 0) {
        float c = 0.0f;
        for (int d = 0; d < 32; ++d) c += ipb[512 + hd * 32 + d] * wp[hd * 32 + d];
        ch[hd] = c;
    }
}

// Bt[j][k] bf16: j<512 -> ipw[j][k]; 512..519 -> u[j-512][k]; else 0.
__global__ __launch_bounds__(256) void k_makeB(const float* __restrict__ ipw,
                                               const float* __restrict__ ipb,
                                               const float* __restrict__ u,
                                               const float* __restrict__ ch,
                                               unsigned short* __restrict__ Bt,
                                               float* __restrict__ b2) {
    int j = blockIdx.x, k = threadIdx.x;
    float v = 0.0f;
    if (j < 512)      v = ipw[(size_t)j * 256 + k];
    else if (j < 520) v = u[(j - 512) * 256 + k];
    Bt[(size_t)j * 256 + k] = f2bf(v);
    if (k == 0) b2[j] = (j < 512) ? ipb[j] : ((j < 520) ? ch[j - 512] : 0.0f);
}

// Fused QKV-GEMM + attention finalize. Block = 64 token rows (32 nodes).
// CT row stride 546 elems (273 dw): 4-row step = 1092 dw = 4 (mod 32) -> conflict-free
// epilogue writes; Phase B reads dword-vectorized.
#define CT_STRIDE 546
__global__ __launch_bounds__(256) void k_fuse(const unsigned short* __restrict__ comb,
                                              const unsigned short* __restrict__ Bt,
                                              const float* __restrict__ b2,
                                              double* __restrict__ accum) {
    __shared__ __align__(16) unsigned short CT[64 * CT_STRIDE];
    __shared__ __align__(16) unsigned short sA[64][40];
    __shared__ __align__(16) unsigned short sB[64][40];
    __shared__ float red[256];

    int tid  = threadIdx.x;
    int lane = tid & 63, wid = tid >> 6;
    int wm = wid >> 1, wn = wid & 1;
    int arow = tid >> 2, aseg = (tid & 3) * 8;
    long grow = (long)blockIdx.x * 64 + arow;
    bool aval = grow < M_ROWS;
    const unsigned short* aptr = comb + grow * 256 + aseg;
    int fr = lane & 15, fk = (lane >> 4) * 8;
    int rb = (lane >> 4) * 4;

    for (int cb = 0; cb < 9; ++cb) {
        const unsigned short* bptr = Bt + ((long)cb * 64 + arow) * 256 + aseg;
        f32x4 acc00 = {0,0,0,0}, acc01 = {0,0,0,0}, acc10 = {0,0,0,0}, acc11 = {0,0,0,0};
        for (int ks = 0; ks < 8; ++ks) {
            uint4 av = aval ? *reinterpret_cast<const uint4*>(aptr + ks * 32) : make_uint4(0,0,0,0);
            uint4 bv = *reinterpret_cast<const uint4*>(bptr + ks * 32);
            __syncthreads();
            *reinterpret_cast<uint4*>(&sA[arow][aseg]) = av;
            *reinterpret_cast<uint4*>(&sB[arow][aseg]) = bv;
            __syncthreads();
            short8v a0 = *reinterpret_cast<const short8v*>(&sA[wm * 32 + fr][fk]);
            short8v a1 = *reinterpret_cast<const short8v*>(&sA[wm * 32 + 16 + fr][fk]);
            short8v b0 = *reinterpret_cast<const short8v*>(&sB[wn * 32 + fr][fk]);
            short8v b1 = *reinterpret_cast<const short8v*>(&sB[wn * 32 + 16 + fr][fk]);
            acc00 = __builtin_amdgcn_mfma_f32_16x16x32_bf16(a0, b0, acc00, 0, 0, 0);
            acc01 = __builtin_amdgcn_mfma_f32_16x16x32_bf16(a0, b1, acc01, 0, 0, 0);
            acc10 = __builtin_amdgcn_mfma_f32_16x16x32_bf16(a1, b0, acc10, 0, 0, 0);
            acc11 = __builtin_amdgcn_mfma_f32_16x16x32_bf16(a1, b1, acc11, 0, 0, 0);
        }
        int ccol = cb * 64 + wn * 32;
        #pragma unroll
        for (int mn = 0; mn < 4; ++mn) {
            int m = mn >> 1, nn = mn & 1;
            f32x4 a = (mn == 0) ? acc00 : (mn == 1) ? acc01 : (mn == 2) ? acc10 : acc11;
            int col = ccol + nn * 16 + (lane & 15);
            if (col < 520) {
                float bias = b2[col];
                int rbase = wm * 32 + m * 16 + rb;
                #pragma unroll
                for (int j = 0; j < 4; ++j)
                    CT[(rbase + j) * CT_STRIDE + col] = f2bf(a[j] + bias);
            }
        }
    }
    __syncthreads();

    // Phase B: 512 items = 32 nodes x 8 heads x 2 query-tokens; 2 items/thread
    float acc = 0.0f;
    #pragma unroll
    for (int ii = 0; ii < 2; ++ii) {
        int it = tid + ii * 256;
        int node32 = it >> 4;
        int rem = it & 15, hd = rem >> 1, t = rem & 1;
        int gnode = blockIdx.x * 32 + node32;
        if (gnode < N_NODES) {
            const unsigned short* qr = &CT[(2 * node32 + t) * CT_STRIDE];
            const unsigned short* k0 = &CT[(2 * node32 + 0) * CT_STRIDE];
            const unsigned short* k1 = &CT[(2 * node32 + 1) * CT_STRIDE];
            const unsigned int* qw  = reinterpret_cast<const unsigned int*>(qr + hd * 32);
            const unsigned int* k0w = reinterpret_cast<const unsigned int*>(k0 + 256 + hd * 32);
            const unsigned int* k1w = reinterpret_cast<const unsigned int*>(k1 + 256 + hd * 32);
            float s0 = 0.0f, s1 = 0.0f;
            #pragma unroll
            for (int dw = 0; dw < 16; ++dw) {
                unsigned int qv = qw[dw], v0 = k0w[dw], v1 = k1w[dw];
                float ql = bf_lo(qv), qh = bf_hi(qv);
                s0 += ql * bf_lo(v0) + qh * bf_hi(v0);
                s1 += ql * bf_lo(v1) + qh * bf_hi(v1);
            }
            const float sc = 0.17677669529663687f;  // 1/sqrt(32)
            s0 *= sc; s1 *= sc;
            float m = fmaxf(s0, s1);
            float e0 = expf(s0 - m), e1 = expf(s1 - m);
            float inv = 1.0f / (e0 + e1);
            float vw0 = bf2f(k0[512 + hd]);
            float vw1 = bf2f(k1[512 + hd]);
            acc += (e0 * vw0 + e1 * vw1) * inv;
        }
    }
    red[tid] = acc;
    __syncthreads();
    for (int s = 128; s > 0; s >>= 1) {
        if (tid < s) red[tid] += red[tid + s];
        __syncthreads();
    }
    if (tid == 0) atomicAdd(accum, (double)red[0]);
}

__global__ __launch_bounds__(256) void k_final(const float* __restrict__ ow,
                                               const float* __restrict__ opb,
                                               const float* __restrict__ ob,
                                               const double* __restrict__ accum,
                                               float* __restrict__ out) {
    __shared__ float red[256];
    int tid = threadIdx.x;
    red[tid] = ow[tid] * opb[tid];
    __syncthreads();
    for (int s = 128; s > 0; s >>= 1) {
        if (tid < s) red[tid] += red[tid + s];
        __syncthreads();
    }
    if (tid == 0)
        out[0] = (float)(accum[0] / (2.0 * N_NODES) + (double)red[0] + (double)ob[0]);
}

// ---------------- launch ----------------
extern "C" void kernel_launch(void* const* d_in, const int* in_sizes, int n_in,
                              void* d_out, int out_size, void* d_ws, size_t ws_size,
                              hipStream_t stream) {
    const float* x   = (const float*)d_in[0];
    const int*   ei  = (const int*)d_in[1];
    const float* Ws  = (const float*)d_in[2];
    const float* bs  = (const float*)d_in[3];
    const float* Wf  = (const float*)d_in[4];
    const float* bf  = (const float*)d_in[5];
    const float* ipw = (const float*)d_in[6];
    const float* ipb = (const float*)d_in[7];
    const float* opw = (const float*)d_in[8];
    const float* opb = (const float*)d_in[9];
    const float* ow  = (const float*)d_in[10];
    const float* ob  = (const float*)d_in[11];
    float* out = (float*)d_out;

    if (ws_size < WS_NEED) { k_guard<<<1, 64, 0, stream>>>(out); return; }

    char* ws = (char*)d_ws;
    unsigned short* xb   = (unsigned short*)(ws + XB_OFF);
    unsigned short* y    = (unsigned short*)(ws + Y_OFF);
    int*            csr  = (int*)           (ws + CSR_OFF);
    unsigned short* comb = (unsigned short*)(ws + COMB_OFF);
    int*            row  = (int*)           (ws + ROW_OFF);
    int*            cnt  = (int*)           (ws + CNT_OFF);
    int*            cur  = (int*)           (ws + CUR_OFF);
    float*          dis  = (float*)         (ws + DIS_OFF);
    float*          dinv = (float*)         (ws + DINV_OFF);
    unsigned short* Bt   = (unsigned short*)(ws + BT_OFF);
    float*          b2   = (float*)         (ws + B2_OFF);
    float*          wp   = (float*)         (ws + WP_OFF);
    float*          u    = (float*)         (ws + U_OFF);
    float*          chv  = (float*)         (ws + CH_OFF);
    int*            flag = (int*)           (ws + FLAG_OFF);
    double*         accum= (double*)        (ws + ACC_OFF);
    unsigned short* Wt2  = (unsigned short*)(ws + WT2_OFF);

    hipMemsetAsync(cnt,   0, (size_t)N_NODES * 4, stream);
    hipMemsetAsync(cur,   0, (size_t)N_NODES * 4, stream);
    hipMemsetAsync(flag,  0, 4, stream);
    hipMemsetAsync(accum, 0, 8, stream);

    k_detect<<<1, 256, 0, stream>>>(ei, flag);
    k_deg   <<<(N_EDGES + 255) / 256, 256, 0, stream>>>(ei, flag, cnt);
    k_norm  <<<(N_NODES + 255) / 256, 256, 0, stream>>>(cnt, dis, dinv);
    k_scan  <<<1, 1024, 0, stream>>>(cnt, row);
    k_place <<<(N_EDGES + 255) / 256, 256, 0, stream>>>(ei, flag, row, cur, csr);

    k_cvtx<<<(N_NODES * 80 + 255) / 256, 256, 0, stream>>>(x, xb);
    k_wt2 <<<512, 256, 0, stream>>>(Ws, Wf, Wt2);

    k_aggx<<<(N_NODES + 3) / 4, 256, 0, stream>>>(csr, row, dis, dinv, xb, y);

    k_wprime<<<1,   256, 0, stream>>>(ow, opw, wp);
    k_u     <<<8,   256, 0, stream>>>(ipw, ipb, wp, u, chv);
    k_makeB <<<576, 256, 0, stream>>>(ipw, ipb, u, chv, Bt, b2);

    dim3 gc(8, (N_NODES + 63) / 64);
    k_comb<<<gc, 256, 0, stream>>>(y, Wt2, bs, bf, comb);

    k_fuse<<<(M_ROWS + 63) / 64, 256, 0, stream>>>(comb, Bt, b2, accum);
    k_final<<<1, 256, 0, stream>>>(ow, opb, ob, accum, out);
}